// Round 1
// baseline (4950.141 us; speedup 1.0000x reference)
//
#include <hip/hip_runtime.h>

// Batched time-varying LQR: Riccati backward pass + forward rollout.
// T=64, B=128, NS=64 (state), NC=32 (control), NSC=96.
// One workgroup (512 threads = 8 waves) per batch element.
//
// R1 latency-attack rewrite:
//  - 512 threads/block: 2 waves/SIMD (was 1) for latency hiding.
//  - All global inputs staged with async global_load_lds; F/c/f double-buffered
//    one timestep ahead, C staged at top-of-iter and hidden under phase B.
//    Counted s_waitcnt vmcnt(N) + raw s_barrier (no __syncthreads -> no forced
//    vmcnt(0) drain). Every wave issues exactly 10 staging instrs/iter.
//  - Q materialized only for rows 64..95 (Qu=[Qux|Quu], Q symmetric); Qxx is
//    folded into the V-update GEMM (V = Cxx + Fx^T W - sym(Qxu S)).
//  - Cholesky (serial, lanes 0-31) overlapped with V W-part GEMM (waves 1-7).

constexpr int T_   = 64;
constexpr int B_   = 128;
constexpr int NS_  = 64;
constexpr int NC_  = 32;
constexpr int NSC_ = 96;

// ---- LDS layout (floats). Total 40320 floats = 161280 B (< 160 KiB). ----
constexpr int OFF_VS    = 0;      // Vs [64][68]    (V, symmetric, stride 68: 272B, 16B-aligned)
constexpr int OFF_WS    = 4352;   // Ws [64][100]   (W = V F; stride 400B aligned)  | fwd: Sfb[2][2304]
constexpr int OFF_QU    = 10752;  // Qu [32][100]   (Q rows 64..95 = [Qux | Quu])
constexpr int OFF_SS    = 13952;  // Ss [32][68]    (S = Quu^{-1} [Qux | qu])
constexpr int OFF_LT    = 16128;  // LT [32][33]    (Cholesky factor, transposed)
constexpr int OFF_INVD  = 17184;  // invd[32]
constexpr int OFF_QV    = 17216;  // qv[96] (+pad)  | fwd: tau[96]
constexpr int OFF_HV    = 17316;  // hv[64]
constexpr int OFF_VV    = 17380;  // vv[64] (+pad)
constexpr int OFF_XNB   = 17448;  // xnb[64] (fwd x_next staging)
constexpr int OFF_FB    = 17536;  // Fbuf [2][6144] (F linear [64][96], global_load_lds dest)
constexpr int OFF_CB    = 29824;  // Cbuf [9216]    (C linear [96][96])
constexpr int OFF_TRASH = 39040;  // trash chunk [256] for clamped C tail chunks
constexpr int OFF_CF    = 39296;  // cfb [2][512]   (c at +0..95, f at +256..319)
constexpr int SMEM_F    = 40320;

typedef __attribute__((address_space(3))) void*       lds_vp;
typedef const __attribute__((address_space(1))) void* gas_vp;

__device__ __forceinline__ void g2l16(const float* g, float* l) {
  // async global->LDS, 16B per lane; LDS dest = wave-uniform base + lane*16
  __builtin_amdgcn_global_load_lds((gas_vp)g, (lds_vp)l, 16, 0, 0);
}

// counted wait + raw barrier: drains LDS ops (visibility) but leaves up to N
// vmem (prefetch) ops in flight across the barrier.
#define WAIT_BAR(S) do { asm volatile("s_waitcnt " S ::: "memory"); \
                         __builtin_amdgcn_s_barrier(); } while (0)

__global__ __launch_bounds__(512, 2) void lqr_all(
    const float* __restrict__ Cg, const float* __restrict__ cvg,
    const float* __restrict__ Fg, const float* __restrict__ fvg,
    const float* __restrict__ x0g, float* __restrict__ outg,
    float* __restrict__ Sws)
{
  const int b    = blockIdx.x;
  const int tid  = threadIdx.x;
  const int wid  = tid >> 6;    // wave id 0..7
  const int lane = tid & 63;

  __shared__ float smem[SMEM_F];
  float (*Vs)[68]  = (float(*)[68]) (smem + OFF_VS);
  float (*Ws)[100] = (float(*)[100])(smem + OFF_WS);
  float (*Qu)[100] = (float(*)[100])(smem + OFF_QU);
  float (*Ss)[68]  = (float(*)[68]) (smem + OFF_SS);
  float (*LT)[33]  = (float(*)[33]) (smem + OFF_LT);
  float* invd = smem + OFF_INVD;
  float* qv   = smem + OFF_QV;
  float* hv   = smem + OFF_HV;
  float* vv   = smem + OFF_VV;

  // init V = 0, v = 0
  for (int e = tid; e < 4352; e += 512) smem[e] = 0.f;
  if (tid < 64) vv[tid] = 0.f;

  // ---- prologue staging: F_{63}, c_{63}, f_{63} -> buffers[0]  (5 instrs/wave)
  {
    const size_t tb0 = (size_t)(T_ - 1) * B_ + b;
    const float* Fbase = Fg + tb0 * (NS_ * NSC_);
#pragma unroll
    for (int r = 0; r < 3; ++r) {
      const int q = wid * 3 + r;                       // 0..23 exact
      g2l16(Fbase + q * 256 + lane * 4, smem + OFF_FB + q * 256);
    }
    const int o = lane * 4;
    g2l16(cvg + tb0 * 96 + (o < 96 ? o : 92), smem + OFF_CF);
    g2l16(fvg + tb0 * 64 + (o < 64 ? o : 60), smem + OFF_CF + 256);
  }

  int cur = 0;

  // ================= backward Riccati pass =================
  for (int t = T_ - 1; t >= 0; --t) {
    const size_t tb = (size_t)t * B_ + b;

    // ---- TOP staging: C_t (5/wave), F_{t-1} (3/wave), c/f_{t-1} (2/wave) = 10
    {
      const float* Cbase = Cg + tb * (NSC_ * NSC_);
#pragma unroll
      for (int r = 0; r < 5; ++r) {
        const int q = wid * 5 + r;                     // 0..39 (36..39 = trash)
        float* dst = (q < 36) ? (smem + OFF_CB + q * 256) : (smem + OFF_TRASH);
        const int off = q * 256 + lane * 4;
        g2l16(Cbase + (off < 9216 ? off : 9212), dst);
      }
      const int tp = (t > 0) ? (t - 1) : 0;            // clamp; keeps counts uniform
      const size_t tbp = (size_t)tp * B_ + b;
      const float* Fbase = Fg + tbp * (NS_ * NSC_);
      float* fdst = smem + OFF_FB + (cur ^ 1) * 6144;
#pragma unroll
      for (int r = 0; r < 3; ++r) {
        const int q = wid * 3 + r;
        g2l16(Fbase + q * 256 + lane * 4, fdst + q * 256);
      }
      float* cdst = smem + OFF_CF + (cur ^ 1) * 512;
      const int o = lane * 4;
      g2l16(cvg + tbp * 96 + (o < 96 ? o : 92), cdst);
      g2l16(fvg + tbp * 64 + (o < 64 ? o : 60), cdst + 256);
    }

    // allow the 10 just-issued to stay in flight; F_t/c_t/f_t (older) complete.
    WAIT_BAR("vmcnt(10) lgkmcnt(0)");

    const float* Fb = smem + OFF_FB + cur * 6144;
    const float* cf = smem + OFF_CF + cur * 512;

    // ---- phase B: W = V F (1x12 tiles, 512 thr); h = v + V f (tid<64)
    {
      const int s  = tid >> 3;
      const int j0 = (tid & 7) * 12;
      float a[12];
#pragma unroll
      for (int j = 0; j < 12; ++j) a[j] = 0.f;
#pragma unroll 4
      for (int u = 0; u < 64; ++u) {
        const float vu = Vs[u][s];
        const float4 b0 = *(const float4*)(Fb + u * 96 + j0);
        const float4 b1 = *(const float4*)(Fb + u * 96 + j0 + 4);
        const float4 b2 = *(const float4*)(Fb + u * 96 + j0 + 8);
        a[0] += vu * b0.x; a[1] += vu * b0.y; a[2]  += vu * b0.z; a[3]  += vu * b0.w;
        a[4] += vu * b1.x; a[5] += vu * b1.y; a[6]  += vu * b1.z; a[7]  += vu * b1.w;
        a[8] += vu * b2.x; a[9] += vu * b2.y; a[10] += vu * b2.z; a[11] += vu * b2.w;
      }
      *(float4*)&Ws[s][j0]     = make_float4(a[0], a[1], a[2],  a[3]);
      *(float4*)&Ws[s][j0 + 4] = make_float4(a[4], a[5], a[6],  a[7]);
      *(float4*)&Ws[s][j0 + 8] = make_float4(a[8], a[9], a[10], a[11]);
    }
    if (tid < 64) {
      float acc = vv[tid];
#pragma unroll 8
      for (int u = 0; u < 64; ++u) acc += Vs[u][tid] * cf[256 + u];
      hv[tid] = acc;
    }

    // C_t (the 5 oldest outstanding) completes here; F/cf_{t-1} stay in flight.
    WAIT_BAR("vmcnt(5) lgkmcnt(0)");

    // ---- phase Qu: Qu = C[64:96,:] + Fu^T W (thr 0..255); q = c + F^T h (256..351)
    if (tid < 256) {
      const int i  = tid >> 3;                 // 0..31
      const int j0 = (tid & 7) * 12;
      float a[12];
      {
        const float* cp = smem + OFF_CB + (64 + i) * 96 + j0;
        const float4 c0 = *(const float4*)(cp);
        const float4 c1 = *(const float4*)(cp + 4);
        const float4 c2 = *(const float4*)(cp + 8);
        a[0] = c0.x; a[1] = c0.y; a[2]  = c0.z; a[3]  = c0.w;
        a[4] = c1.x; a[5] = c1.y; a[6]  = c1.z; a[7]  = c1.w;
        a[8] = c2.x; a[9] = c2.y; a[10] = c2.z; a[11] = c2.w;
      }
#pragma unroll 4
      for (int s2 = 0; s2 < 64; ++s2) {
        const float fu = Fb[s2 * 96 + 64 + i];
        const float4 w0 = *(const float4*)&Ws[s2][j0];
        const float4 w1 = *(const float4*)&Ws[s2][j0 + 4];
        const float4 w2 = *(const float4*)&Ws[s2][j0 + 8];
        a[0] += fu * w0.x; a[1] += fu * w0.y; a[2]  += fu * w0.z; a[3]  += fu * w0.w;
        a[4] += fu * w1.x; a[5] += fu * w1.y; a[6]  += fu * w1.z; a[7]  += fu * w1.w;
        a[8] += fu * w2.x; a[9] += fu * w2.y; a[10] += fu * w2.z; a[11] += fu * w2.w;
      }
      *(float4*)&Qu[i][j0]     = make_float4(a[0], a[1], a[2],  a[3]);
      *(float4*)&Qu[i][j0 + 4] = make_float4(a[4], a[5], a[6],  a[7]);
      *(float4*)&Qu[i][j0 + 8] = make_float4(a[8], a[9], a[10], a[11]);
    } else if (tid < 352) {
      const int j = tid - 256;                 // 0..95
      float acc = cf[j];
#pragma unroll 8
      for (int s2 = 0; s2 < 64; ++s2) acc += Fb[s2 * 96 + j] * hv[s2];
      qv[j] = acc;
    }

    WAIT_BAR("lgkmcnt(0)");

    // ---- phase D window: Cholesky of Quu (lanes 0-31)  ||  V W-part (tid>=65)
    const int vr = tid >> 4, vc = tid & 15;
    const int vi0 = vr * 2, vj0 = vc * 4;      // V tile: rows vi0..vi0+1, cols vj0..vj0+3
    float wp[2][4] = {{0.f, 0.f, 0.f, 0.f}, {0.f, 0.f, 0.f, 0.f}};
    auto vpart = [&]() {                        // wp += Fx^T W  (my tile)
#pragma unroll 4
      for (int s2 = 0; s2 < 64; ++s2) {
        const float2 fa = *(const float2*)(Fb + s2 * 96 + vi0);
        const float4 w4 = *(const float4*)&Ws[s2][vj0];
        const float fv2[2] = {fa.x, fa.y};
        const float wv[4]  = {w4.x, w4.y, w4.z, w4.w};
#pragma unroll
        for (int aa = 0; aa < 2; ++aa)
#pragma unroll
          for (int jj = 0; jj < 4; ++jj) wp[aa][jj] += fv2[aa] * wv[jj];
      }
    };
    if (tid < 32) {
      const int i = tid;
      for (int j = 0; j < 32; ++j) {
        float dot = 0.f;
        for (int k = 0; k < j; ++k) dot += LT[k][i] * LT[k][j];
        const float dj  = __shfl(dot, j);
        const float d   = Qu[j][64 + j] - dj;
        const float rin = 1.0f / sqrtf(d);
        if (i == j) invd[j] = rin;
        if (i >= j) {
          const float val = (i == j) ? d * rin : (Qu[i][64 + j] - dot) * rin;
          LT[j][i] = val;
        }
      }
    } else if (tid >= 65) {
      vpart();
    }

    WAIT_BAR("lgkmcnt(0)");

    // ---- phase E: S = Quu^{-1} [Qux | qu], one thread per RHS column (65)
    if (tid < 65) {
      float xr[32];
#pragma unroll
      for (int i2 = 0; i2 < 32; ++i2) {
        float v = (tid < 64) ? Qu[i2][tid] : qv[64 + i2];
#pragma unroll
        for (int k = 0; k < i2; ++k) v -= LT[k][i2] * xr[k];
        xr[i2] = v * invd[i2];
      }
#pragma unroll
      for (int i2 = 31; i2 >= 0; --i2) {
        float v = xr[i2];
#pragma unroll
        for (int k = i2 + 1; k < 32; ++k) v -= LT[i2][k] * xr[k];
        xr[i2] = v * invd[i2];
      }
      float* Sg = Sws + tb * 2080;             // [32][65] linear per (t,b)
#pragma unroll
      for (int i2 = 0; i2 < 32; ++i2) {
        Ss[i2][tid]       = xr[i2];
        Sg[i2 * 65 + tid] = xr[i2];
      }
    }

    WAIT_BAR("lgkmcnt(0)");

    // ---- phase F: V = Cxx + Fx^T W - 0.5*(B + B^T),  B = Qxu S ; vn
    if (tid < 65) vpart();                     // these threads were busy in D/E
    {
      float bp[2][4] = {{0.f, 0.f, 0.f, 0.f}, {0.f, 0.f, 0.f, 0.f}};
      float bt[2][4] = {{0.f, 0.f, 0.f, 0.f}, {0.f, 0.f, 0.f, 0.f}};
#pragma unroll 4
      for (int m = 0; m < 32; ++m) {
        const float2 qa = *(const float2*)&Qu[m][vi0];   // Qxu[vi0..][m]
        const float4 sb = *(const float4*)&Ss[m][vj0];
        const float4 qb = *(const float4*)&Qu[m][vj0];   // Qxu[vj0..][m]
        const float2 sa = *(const float2*)&Ss[m][vi0];
        const float qav[2] = {qa.x, qa.y};
        const float sbv[4] = {sb.x, sb.y, sb.z, sb.w};
        const float qbv[4] = {qb.x, qb.y, qb.z, qb.w};
        const float sav[2] = {sa.x, sa.y};
#pragma unroll
        for (int aa = 0; aa < 2; ++aa)
#pragma unroll
          for (int jj = 0; jj < 4; ++jj) {
            bp[aa][jj] += qav[aa] * sbv[jj];   // B[i][j]
            bt[aa][jj] += qbv[jj] * sav[aa];   // B[j][i]
          }
      }
#pragma unroll
      for (int aa = 0; aa < 2; ++aa) {
        const float4 cx = *(const float4*)(smem + OFF_CB + (vi0 + aa) * 96 + vj0);
        const float cxv[4] = {cx.x, cx.y, cx.z, cx.w};
        float o[4];
#pragma unroll
        for (int jj = 0; jj < 4; ++jj)
          o[jj] = cxv[jj] + wp[aa][jj] - 0.5f * (bp[aa][jj] + bt[aa][jj]);
        *(float4*)&Vs[vi0 + aa][vj0] = make_float4(o[0], o[1], o[2], o[3]);
      }
    }
    if (tid < 64) {                            // vn = qx - Qxu S[:,64]
      float acc = qv[tid];
#pragma unroll 8
      for (int m = 0; m < 32; ++m) acc -= Qu[m][tid] * Ss[m][64];
      vv[tid] = acc;
    }

    WAIT_BAR("lgkmcnt(0)");
    cur ^= 1;
  }

  // ================= forward rollout =================
  WAIT_BAR("vmcnt(0) lgkmcnt(0)");             // drain S stores + dangling prefetch
  float* tf  = smem + OFF_QV;                  // tau: [0:64]=x, [64:96]=u
  float* xnb = smem + OFF_XNB;
  if (tid < 64) tf[tid] = x0g[(size_t)b * 64 + tid];

  auto stage_fwd = [&](int ts, int nb) {       // 6 instrs/wave: S(2) F(3) f(1)
    const size_t tbs = (size_t)ts * B_ + b;
    const float* Sb = Sws + tbs * 2080;
    float* sdst = smem + OFF_WS + nb * 2304;   // Sfb alias on Ws region
#pragma unroll
    for (int r = 0; r < 2; ++r) {
      int q = wid * 2 + r; if (q > 8) q = 8;   // 9 chunks, dup tail (benign)
      const int off = q * 256 + lane * 4;
      g2l16(Sb + (off < 2080 ? off : 2076), sdst + q * 256);
    }
    const float* Fbase = Fg + tbs * (NS_ * NSC_);
    float* fdst = smem + OFF_FB + nb * 6144;
#pragma unroll
    for (int r = 0; r < 3; ++r) {
      const int q = wid * 3 + r;
      g2l16(Fbase + q * 256 + lane * 4, fdst + q * 256);
    }
    const int o = lane * 4;
    g2l16(fvg + tbs * 64 + (o < 64 ? o : 60), smem + OFF_CF + nb * 512);
  };

  stage_fwd(0, 0);
  cur = 0;
  for (int t = 0; t < T_; ++t) {
    const size_t tb = (size_t)t * B_ + b;
    stage_fwd((t < T_ - 1) ? t + 1 : T_ - 1, cur ^ 1);
    WAIT_BAR("vmcnt(6) lgkmcnt(0)");           // S_t, F_t, f_t ready; tf visible

    // u = -(S[:, :64] x + S[:, 64]) : 8 threads per row, shuffle-reduce
    if (tid < 256) {
      const int m = tid >> 3, l8 = tid & 7;
      const float* Sr = smem + OFF_WS + cur * 2304 + m * 65;
      float p = (l8 == 0) ? Sr[64] : 0.f;
      const int i0 = l8 * 8;
#pragma unroll
      for (int ii = 0; ii < 8; ++ii) p += Sr[i0 + ii] * tf[i0 + ii];
      p += __shfl_xor(p, 1); p += __shfl_xor(p, 2); p += __shfl_xor(p, 4);
      if (l8 == 0) tf[64 + m] = -p;
    }
    WAIT_BAR("lgkmcnt(0)");

    // emit tau; x_next = F tau + f : 8 threads per state row
    if (tid < 96) outg[tb * 96 + tid] = tf[tid];
    {
      const int s2 = tid >> 3, l8 = tid & 7;
      const float* Fr = smem + OFF_FB + cur * 6144 + s2 * 96 + l8 * 12;
      const float4 f0 = *(const float4*)(Fr);
      const float4 f1 = *(const float4*)(Fr + 4);
      const float4 f2 = *(const float4*)(Fr + 8);
      const int i0 = l8 * 12;
      float p = f0.x * tf[i0]     + f0.y * tf[i0 + 1] + f0.z * tf[i0 + 2]  + f0.w * tf[i0 + 3]
              + f1.x * tf[i0 + 4] + f1.y * tf[i0 + 5] + f1.z * tf[i0 + 6]  + f1.w * tf[i0 + 7]
              + f2.x * tf[i0 + 8] + f2.y * tf[i0 + 9] + f2.z * tf[i0 + 10] + f2.w * tf[i0 + 11];
      p += __shfl_xor(p, 1); p += __shfl_xor(p, 2); p += __shfl_xor(p, 4);
      if (l8 == 0) xnb[s2] = p + *(smem + OFF_CF + cur * 512 + s2);
    }
    WAIT_BAR("lgkmcnt(0)");
    if (tid < 64) tf[tid] = xnb[tid];
    cur ^= 1;
  }
}

extern "C" void kernel_launch(void* const* d_in, const int* in_sizes, int n_in,
                              void* d_out, int out_size, void* d_ws, size_t ws_size,
                              hipStream_t stream) {
  const float* C  = (const float*)d_in[0];
  const float* c  = (const float*)d_in[1];
  const float* F  = (const float*)d_in[2];
  const float* f  = (const float*)d_in[3];
  const float* x0 = (const float*)d_in[4];
  float* out = (float*)d_out;
  float* S   = (float*)d_ws;   // needs T*B*32*65*4 = 68.2 MB

  lqr_all<<<dim3(B_), dim3(512), 0, stream>>>(C, c, F, f, x0, out, S);
}

// Round 2
// 2995.610 us; speedup vs baseline: 1.6525x; 1.6525x over previous
//
#include <hip/hip_runtime.h>

// Batched time-varying LQR: Riccati backward pass + forward rollout.
// T=64, B=128, NS=64 (state), NC=32 (control), NSC=96.
// One workgroup (512 threads = 8 waves) per batch element.
//
// R2:
//  - __launch_bounds__(512) plain: R1's (512,2) capped VGPR at 128 -> scratch
//    spills (774 MB WRITE_SIZE). LDS limits us to 1 block/CU anyway.
//  - Y-form Riccati: Y = L^{-1}[Qux|qu]; V = Cxx + Fx^T W - Y^T Y (exactly
//    symmetric); vn = qx - Y^T y. Back-solve (S = L^{-T} Y, rollout-only)
//    deferred one step and run by wave 1 CONCURRENTLY with the next
//    Cholesky (double-buffered Y/LT/invd).
//  - Waves 4-7 compute Vs = Cxx + Fx^T W during the Cholesky window; Cxx via
//    float4 register loads issued at top-of-iteration (latency hidden).
//    C LDS staging shrinks to rows 64..95 (12 exact 1KB chunks).
//  - Async global_load_lds staging with counted s_waitcnt vmcnt(N) + raw
//    s_barrier throughout (never drains the prefetch queue).

constexpr int T_   = 64;
constexpr int B_   = 128;
constexpr int NS_  = 64;
constexpr int NC_  = 32;
constexpr int NSC_ = 96;

// ---- LDS layout (floats). Total 37160 floats = 148,640 B. ----
constexpr int OFF_VS   = 0;       // Vs [64][68]   (V, symmetric, stride 68)
constexpr int OFF_WS   = 4352;    // Ws [64][100]  (W = V F)  | fwd: Sfb[2][2304]
constexpr int OFF_QU   = 10752;   // Qu [32][100]  (Q rows 64..95 = [Qux|Quu])
constexpr int OFF_SS   = 13952;   // Ss [2][32][68] (Y buffers, double-buffered)
constexpr int OFF_LT   = 18304;   // LT [2][32][33] (chol factor^T, dbuf)
constexpr int OFF_INVD = 20416;   // invd[2][32]
constexpr int OFF_QV   = 20480;   // qv[96]+pad    | fwd: tau[96]
constexpr int OFF_HV   = 20580;   // hv[64]
constexpr int OFF_VV   = 20644;   // vv[64]+pad
constexpr int OFF_XNB  = 20712;   // xnb[64]
constexpr int OFF_FB   = 20776;   // Fbuf[2][6144] (F linear [64][96])
constexpr int OFF_CU   = 33064;   // Cu [3072]     (C rows 64..95, linear [32][96])
constexpr int OFF_CF   = 36136;   // cfb[2][512]   (c @ +0..95, f @ +256..319)
constexpr int SMEM_F   = 37160;

typedef __attribute__((address_space(3))) void*       lds_vp;
typedef const __attribute__((address_space(1))) void* gas_vp;

__device__ __forceinline__ void g2l16(const float* g, float* l) {
  // async global->LDS, 16B/lane; LDS dest = wave-uniform base + lane*16
  __builtin_amdgcn_global_load_lds((gas_vp)g, (lds_vp)l, 16, 0, 0);
}

#define ASM_WAIT(S) asm volatile("s_waitcnt " S ::: "memory")
#define BAR()       __builtin_amdgcn_s_barrier()

__global__ __launch_bounds__(512) void lqr_all(
    const float* __restrict__ Cg, const float* __restrict__ cvg,
    const float* __restrict__ Fg, const float* __restrict__ fvg,
    const float* __restrict__ x0g, float* __restrict__ outg,
    float* __restrict__ Sws)
{
  const int b    = blockIdx.x;
  const int tid  = threadIdx.x;
  const int wid  = tid >> 6;
  const int lane = tid & 63;

  __shared__ float smem[SMEM_F];
  float (*Vs)[68]  = (float(*)[68]) (smem + OFF_VS);
  float (*Ws)[100] = (float(*)[100])(smem + OFF_WS);
  float (*Qu)[100] = (float(*)[100])(smem + OFF_QU);
  float* qv = smem + OFF_QV;
  float* hv = smem + OFF_HV;
  float* vv = smem + OFF_VV;

  // init V = 0, v = 0
  for (int e = tid; e < 4352; e += 512) smem[e] = 0.f;
  if (tid < 64) vv[tid] = 0.f;

  // deferred back-solve: S = L^{-T} Y from buffer pb, store to Sws for tbn
  auto backsolve = [&](int pb, size_t tbn, int col) {
    const float (*Sp)[68]  = (const float(*)[68])(smem + OFF_SS + pb * 2176);
    const float (*LTp)[33] = (const float(*)[33])(smem + OFF_LT + pb * 1056);
    const float* ivp = smem + OFF_INVD + pb * 32;
    float xr[32];
#pragma unroll
    for (int i = 0; i < 32; ++i) xr[i] = Sp[i][col];
#pragma unroll
    for (int i = 31; i >= 0; --i) {
      float v = xr[i];
#pragma unroll
      for (int k = i + 1; k < 32; ++k) v -= LTp[i][k] * xr[k];  // L^T
      xr[i] = v * ivp[i];
    }
    float* Sg = Sws + tbn * 2080;
#pragma unroll
    for (int i = 0; i < 32; ++i) Sg[i * 65 + col] = xr[i];
  };

  // ---- prologue staging: F_63, c_63, f_63 -> buffers[0] (5 instrs/wave)
  {
    const size_t tb0 = (size_t)(T_ - 1) * B_ + b;
    const float* Fbase = Fg + tb0 * (NS_ * NSC_);
#pragma unroll
    for (int r = 0; r < 3; ++r) {
      const int q = wid * 3 + r;                 // 0..23 exact
      g2l16(Fbase + q * 256 + lane * 4, smem + OFF_FB + q * 256);
    }
    const int o = lane * 4;
    g2l16(cvg + tb0 * 96 + (o < 96 ? o : 92), smem + OFF_CF);
    g2l16(fvg + tb0 * 64 + (o < 64 ? o : 60), smem + OFF_CF + 256);
  }

  int cur = 0;

  // Vs-update tile for waves 4-7 (2 rows x 8 cols), VsD = Cxx + Fx^T W
  const int tl   = (tid >= 256) ? (tid - 256) : 0;
  const int trow = (tl >> 3) * 2;                // 0..62
  const int tcol = (tl & 7) * 8;                 // 0..56

  // ================= backward Riccati pass =================
  for (int t = T_ - 1; t >= 0; --t) {
    const size_t tb = (size_t)t * B_ + b;

    float4 cxa0, cxa1, cxb0, cxb1;               // Cxx regs (waves 4-7)

    // ---- TOP staging. waves 0-3: 7 async; waves 4-7: 6 async + 4 reg loads
    {
      const float* CuB = Cg + tb * 9216 + 64 * 96;   // C rows 64..95
      if (wid < 4) {
        g2l16(CuB + (wid * 2)     * 256 + lane * 4, smem + OFF_CU + (wid * 2)     * 256);
        g2l16(CuB + (wid * 2 + 1) * 256 + lane * 4, smem + OFF_CU + (wid * 2 + 1) * 256);
      } else {
        g2l16(CuB + (4 + wid) * 256 + lane * 4, smem + OFF_CU + (4 + wid) * 256);
        const float* Cb = Cg + tb * 9216;
        cxa0 = *(const float4*)(Cb + trow * 96 + tcol);
        cxa1 = *(const float4*)(Cb + trow * 96 + tcol + 4);
        cxb0 = *(const float4*)(Cb + (trow + 1) * 96 + tcol);
        cxb1 = *(const float4*)(Cb + (trow + 1) * 96 + tcol + 4);
      }
      const int tp = (t > 0) ? (t - 1) : 0;      // clamp keeps counts uniform
      const size_t tbp = (size_t)tp * B_ + b;
      const float* Fbase = Fg + tbp * (NS_ * NSC_);
      float* fdst = smem + OFF_FB + (cur ^ 1) * 6144;
#pragma unroll
      for (int r = 0; r < 3; ++r) {
        const int q = wid * 3 + r;
        g2l16(Fbase + q * 256 + lane * 4, fdst + q * 256);
      }
      float* cdst = smem + OFF_CF + (cur ^ 1) * 512;
      const int o = lane * 4;
      g2l16(cvg + tbp * 96 + (o < 96 ? o : 92), cdst);
      g2l16(fvg + tbp * 64 + (o < 64 ? o : 60), cdst + 256);
    }

    // W#1: drain prev-iter leftover (F_t, cf_t = oldest 5); keep new in flight
    if (wid < 4) { ASM_WAIT("vmcnt(7) lgkmcnt(0)"); } else { ASM_WAIT("vmcnt(10) lgkmcnt(0)"); }
    BAR();

    const float* Fb = smem + OFF_FB + cur * 6144;
    const float* cf = smem + OFF_CF + cur * 512;

    // ---- phase B: W = V F (all 512, 1x12 tiles); h = v + V f (tid<64 extra)
    {
      const int s  = tid >> 3;
      const int j0 = (tid & 7) * 12;
      float a[12];
#pragma unroll
      for (int j = 0; j < 12; ++j) a[j] = 0.f;
#pragma unroll 4
      for (int u = 0; u < 64; ++u) {
        const float vu = Vs[u][s];
        const float4 b0 = *(const float4*)(Fb + u * 96 + j0);
        const float4 b1 = *(const float4*)(Fb + u * 96 + j0 + 4);
        const float4 b2 = *(const float4*)(Fb + u * 96 + j0 + 8);
        a[0] += vu * b0.x; a[1] += vu * b0.y; a[2]  += vu * b0.z; a[3]  += vu * b0.w;
        a[4] += vu * b1.x; a[5] += vu * b1.y; a[6]  += vu * b1.z; a[7]  += vu * b1.w;
        a[8] += vu * b2.x; a[9] += vu * b2.y; a[10] += vu * b2.z; a[11] += vu * b2.w;
      }
      *(float4*)&Ws[s][j0]     = make_float4(a[0], a[1], a[2],  a[3]);
      *(float4*)&Ws[s][j0 + 4] = make_float4(a[4], a[5], a[6],  a[7]);
      *(float4*)&Ws[s][j0 + 8] = make_float4(a[8], a[9], a[10], a[11]);
    }
    if (tid < 64) {
      float acc = vv[tid];
#pragma unroll 8
      for (int u = 0; u < 64; ++u) acc += Vs[u][tid] * cf[256 + u];
      hv[tid] = acc;
    }

    // W#2: Cu (and Cxx reg loads) complete; keep F/cf_{t-1} (5) in flight
    ASM_WAIT("vmcnt(5) lgkmcnt(0)");
    BAR();

    // ---- phase Qu: Qu = C[64:96,:] + Fu^T W (tid<256); q = c + F^T h (256..351)
    if (tid < 256) {
      const int i  = tid >> 3;                   // 0..31
      const int j0 = (tid & 7) * 12;
      float a[12];
      {
        const float* cp = smem + OFF_CU + i * 96 + j0;
        const float4 c0 = *(const float4*)(cp);
        const float4 c1 = *(const float4*)(cp + 4);
        const float4 c2 = *(const float4*)(cp + 8);
        a[0] = c0.x; a[1] = c0.y; a[2]  = c0.z; a[3]  = c0.w;
        a[4] = c1.x; a[5] = c1.y; a[6]  = c1.z; a[7]  = c1.w;
        a[8] = c2.x; a[9] = c2.y; a[10] = c2.z; a[11] = c2.w;
      }
#pragma unroll 4
      for (int s2 = 0; s2 < 64; ++s2) {
        const float fu = Fb[s2 * 96 + 64 + i];
        const float4 w0 = *(const float4*)&Ws[s2][j0];
        const float4 w1 = *(const float4*)&Ws[s2][j0 + 4];
        const float4 w2 = *(const float4*)&Ws[s2][j0 + 8];
        a[0] += fu * w0.x; a[1] += fu * w0.y; a[2]  += fu * w0.z; a[3]  += fu * w0.w;
        a[4] += fu * w1.x; a[5] += fu * w1.y; a[6]  += fu * w1.z; a[7]  += fu * w1.w;
        a[8] += fu * w2.x; a[9] += fu * w2.y; a[10] += fu * w2.z; a[11] += fu * w2.w;
      }
      *(float4*)&Qu[i][j0]     = make_float4(a[0], a[1], a[2],  a[3]);
      *(float4*)&Qu[i][j0 + 4] = make_float4(a[4], a[5], a[6],  a[7]);
      *(float4*)&Qu[i][j0 + 8] = make_float4(a[8], a[9], a[10], a[11]);
    } else if (tid < 352) {
      const int j = tid - 256;                   // 0..95
      float acc = cf[j];
#pragma unroll 8
      for (int s2 = 0; s2 < 64; ++s2) acc += Fb[s2 * 96 + j] * hv[s2];
      qv[j] = acc;
    }

    ASM_WAIT("lgkmcnt(0)");
    BAR();

    // ---- phase D (3-way concurrent):
    //   wave 0 lanes 0-31 : Cholesky Quu = L L^T  -> LT[cur], invd[cur]
    //   wave 1 (+tid 128) : deferred back-solve of Y_{t+1} -> Sws (skip t=63)
    //   waves 4-7         : Vs = Cxx + Fx^T W   (VsD)
    if (tid < 32) {
      float (*LTc)[33] = (float(*)[33])(smem + OFF_LT + cur * 1056);
      float* ivc = smem + OFF_INVD + cur * 32;
      const int i = tid;
      for (int j = 0; j < 32; ++j) {
        float dot = 0.f;
        for (int k = 0; k < j; ++k) dot += LTc[k][i] * LTc[k][j];
        const float dj  = __shfl(dot, j);
        const float d   = Qu[j][64 + j] - dj;
        const float rin = 1.0f / sqrtf(d);
        if (i == j) ivc[j] = rin;
        if (i >= j) {
          const float val = (i == j) ? d * rin : (Qu[i][64 + j] - dot) * rin;
          LTc[j][i] = val;
        }
      }
    }
    if (tid >= 64 && tid <= 128 && t != T_ - 1) {
      backsolve(cur ^ 1, (size_t)(t + 1) * B_ + b, tid - 64);
    }
    if (tid >= 256) {
      float a0[8], a1[8];
      a0[0]=cxa0.x; a0[1]=cxa0.y; a0[2]=cxa0.z; a0[3]=cxa0.w;
      a0[4]=cxa1.x; a0[5]=cxa1.y; a0[6]=cxa1.z; a0[7]=cxa1.w;
      a1[0]=cxb0.x; a1[1]=cxb0.y; a1[2]=cxb0.z; a1[3]=cxb0.w;
      a1[4]=cxb1.x; a1[5]=cxb1.y; a1[6]=cxb1.z; a1[7]=cxb1.w;
#pragma unroll 4
      for (int u = 0; u < 64; ++u) {
        const float2 fx = *(const float2*)(Fb + u * 96 + trow);
        const float4 w0 = *(const float4*)&Ws[u][tcol];
        const float4 w1 = *(const float4*)&Ws[u][tcol + 4];
        a0[0] += fx.x * w0.x; a0[1] += fx.x * w0.y; a0[2] += fx.x * w0.z; a0[3] += fx.x * w0.w;
        a0[4] += fx.x * w1.x; a0[5] += fx.x * w1.y; a0[6] += fx.x * w1.z; a0[7] += fx.x * w1.w;
        a1[0] += fx.y * w0.x; a1[1] += fx.y * w0.y; a1[2] += fx.y * w0.z; a1[3] += fx.y * w0.w;
        a1[4] += fx.y * w1.x; a1[5] += fx.y * w1.y; a1[6] += fx.y * w1.z; a1[7] += fx.y * w1.w;
      }
      *(float4*)&Vs[trow][tcol]         = make_float4(a0[0], a0[1], a0[2], a0[3]);
      *(float4*)&Vs[trow][tcol + 4]     = make_float4(a0[4], a0[5], a0[6], a0[7]);
      *(float4*)&Vs[trow + 1][tcol]     = make_float4(a1[0], a1[1], a1[2], a1[3]);
      *(float4*)&Vs[trow + 1][tcol + 4] = make_float4(a1[4], a1[5], a1[6], a1[7]);
    }

    ASM_WAIT("lgkmcnt(0)");
    BAR();

    // ---- phase E: forward solve Y = L^{-1}[Qux | qu] (tid<65) -> Ss[cur]
    if (tid < 65) {
      const float (*LTc)[33] = (const float(*)[33])(smem + OFF_LT + cur * 1056);
      const float* ivc = smem + OFF_INVD + cur * 32;
      float xr[32];
#pragma unroll
      for (int i = 0; i < 32; ++i) {
        float v = (tid < 64) ? Qu[i][tid] : qv[64 + i];
#pragma unroll
        for (int k = 0; k < i; ++k) v -= LTc[k][i] * xr[k];
        xr[i] = v * ivc[i];
      }
      float (*Sc)[68] = (float(*)[68])(smem + OFF_SS + cur * 2176);
#pragma unroll
      for (int i = 0; i < 32; ++i) Sc[i][tid] = xr[i];
    }

    ASM_WAIT("lgkmcnt(0)");
    BAR();

    // ---- phase F: V = VsD - Y^T Y (all 512, 2x4 tiles); vn = qx - Y^T y
    {
      const int vi0 = (tid >> 4) * 2, vj0 = (tid & 15) * 4;
      const float (*Sc)[68] = (const float(*)[68])(smem + OFF_SS + cur * 2176);
      float p0[4] = {0.f, 0.f, 0.f, 0.f}, p1[4] = {0.f, 0.f, 0.f, 0.f};
#pragma unroll 4
      for (int m = 0; m < 32; ++m) {
        const float2 ya = *(const float2*)&Sc[m][vi0];
        const float4 yb = *(const float4*)&Sc[m][vj0];
        p0[0] += ya.x * yb.x; p0[1] += ya.x * yb.y; p0[2] += ya.x * yb.z; p0[3] += ya.x * yb.w;
        p1[0] += ya.y * yb.x; p1[1] += ya.y * yb.y; p1[2] += ya.y * yb.z; p1[3] += ya.y * yb.w;
      }
      float4 v0 = *(const float4*)&Vs[vi0][vj0];
      float4 v1 = *(const float4*)&Vs[vi0 + 1][vj0];
      v0.x -= p0[0]; v0.y -= p0[1]; v0.z -= p0[2]; v0.w -= p0[3];
      v1.x -= p1[0]; v1.y -= p1[1]; v1.z -= p1[2]; v1.w -= p1[3];
      *(float4*)&Vs[vi0][vj0]     = v0;
      *(float4*)&Vs[vi0 + 1][vj0] = v1;
    }
    if (tid < 64) {
      const float (*Sc)[68] = (const float(*)[68])(smem + OFF_SS + cur * 2176);
      float acc = qv[tid];
#pragma unroll 4
      for (int m = 0; m < 32; ++m) acc -= Sc[m][tid] * Sc[m][64];
      vv[tid] = acc;
    }

    ASM_WAIT("lgkmcnt(0)");
    BAR();
    cur ^= 1;
  }

  // ---- epilogue: back-solve for t=0 (its Y/LT/invd live in buffer 1)
  ASM_WAIT("vmcnt(0) lgkmcnt(0)");
  BAR();
  if (tid < 65) backsolve(1, (size_t)b, tid);
  ASM_WAIT("vmcnt(0) lgkmcnt(0)");   // S stores must land before fwd re-reads
  BAR();

  // ================= forward rollout =================
  float* tf  = smem + OFF_QV;                    // tau: [0:64]=x, [64:96]=u
  float* xnb = smem + OFF_XNB;
  if (tid < 64) tf[tid] = x0g[(size_t)b * 64 + tid];

  auto stage_fwd = [&](int ts, int nb) {         // 6 instrs/wave: S(2) F(3) f(1)
    const size_t tbs = (size_t)ts * B_ + b;
    const float* Sb = Sws + tbs * 2080;
    float* sdst = smem + OFF_WS + nb * 2304;
#pragma unroll
    for (int r = 0; r < 2; ++r) {
      int q = wid * 2 + r; if (q > 8) q = 8;     // 9 chunks, dup tail (benign)
      const int off = q * 256 + lane * 4;
      g2l16(Sb + (off < 2080 ? off : 2076), sdst + q * 256);
    }
    const float* Fbase = Fg + tbs * (NS_ * NSC_);
    float* fdst = smem + OFF_FB + nb * 6144;
#pragma unroll
    for (int r = 0; r < 3; ++r) {
      const int q = wid * 3 + r;
      g2l16(Fbase + q * 256 + lane * 4, fdst + q * 256);
    }
    const int o = lane * 4;
    g2l16(fvg + tbs * 64 + (o < 64 ? o : 60), smem + OFF_CF + nb * 512);
  };

  stage_fwd(0, 0);
  cur = 0;
  for (int t = 0; t < T_; ++t) {
    const size_t tb = (size_t)t * B_ + b;
    stage_fwd((t < T_ - 1) ? t + 1 : T_ - 1, cur ^ 1);
    ASM_WAIT("vmcnt(6) lgkmcnt(0)");             // S_t, F_t, f_t ready
    BAR();

    // u = -(S[:, :64] x + S[:, 64]) : 8 threads per control row
    if (tid < 256) {
      const int m = tid >> 3, l8 = tid & 7;
      const float* Sr = smem + OFF_WS + cur * 2304 + m * 65;
      float p = (l8 == 0) ? Sr[64] : 0.f;
      const int i0 = l8 * 8;
#pragma unroll
      for (int ii = 0; ii < 8; ++ii) p += Sr[i0 + ii] * tf[i0 + ii];
      p += __shfl_xor(p, 1); p += __shfl_xor(p, 2); p += __shfl_xor(p, 4);
      if (l8 == 0) tf[64 + m] = -p;
    }
    ASM_WAIT("lgkmcnt(0)");
    BAR();

    // emit tau; x_next = F tau + f : 8 threads per state row
    if (tid < 96) outg[tb * 96 + tid] = tf[tid];
    {
      const int s2 = tid >> 3, l8 = tid & 7;
      const float* Fr = smem + OFF_FB + cur * 6144 + s2 * 96 + l8 * 12;
      const float4 f0 = *(const float4*)(Fr);
      const float4 f1 = *(const float4*)(Fr + 4);
      const float4 f2 = *(const float4*)(Fr + 8);
      const int i0 = l8 * 12;
      float p = f0.x * tf[i0]     + f0.y * tf[i0 + 1] + f0.z * tf[i0 + 2]  + f0.w * tf[i0 + 3]
              + f1.x * tf[i0 + 4] + f1.y * tf[i0 + 5] + f1.z * tf[i0 + 6]  + f1.w * tf[i0 + 7]
              + f2.x * tf[i0 + 8] + f2.y * tf[i0 + 9] + f2.z * tf[i0 + 10] + f2.w * tf[i0 + 11];
      p += __shfl_xor(p, 1); p += __shfl_xor(p, 2); p += __shfl_xor(p, 4);
      if (l8 == 0) xnb[s2] = p + *(smem + OFF_CF + cur * 512 + s2);
    }
    ASM_WAIT("lgkmcnt(0)");
    BAR();
    if (tid < 64) tf[tid] = xnb[tid];
    cur ^= 1;
  }
}

extern "C" void kernel_launch(void* const* d_in, const int* in_sizes, int n_in,
                              void* d_out, int out_size, void* d_ws, size_t ws_size,
                              hipStream_t stream) {
  const float* C  = (const float*)d_in[0];
  const float* c  = (const float*)d_in[1];
  const float* F  = (const float*)d_in[2];
  const float* f  = (const float*)d_in[3];
  const float* x0 = (const float*)d_in[4];
  float* out = (float*)d_out;
  float* S   = (float*)d_ws;   // needs T*B*32*65*4 = 68.2 MB

  lqr_all<<<dim3(B_), dim3(512), 0, stream>>>(C, c, F, f, x0, out, S);
}

// Round 3
// 1742.075 us; speedup vs baseline: 2.8415x; 1.7196x over previous
//
#include <hip/hip_runtime.h>

// Batched time-varying LQR: Riccati backward pass + forward rollout.
// T=64, B=128, NS=64 (state), NC=32 (control), NSC=96.
// One workgroup (512 threads = 8 waves) per batch element.
//
// R3:
//  - Register-resident wave-parallel Cholesky (lane i = row i, readlane
//    broadcasts, rank-1 updates in VGPRs). R2's LDS-RAW serial loop was
//    ~130 cy x 496 iters ~= 27 us/step -- the dominant cost all along.
//  - Phase rebalance: VsD (Cxx + Fx^T W, waves 4-7) runs concurrently with
//    the Qu GEMM (waves 0-3); q = c + F^T h moved into the Cholesky window
//    (tids 129-224) next to chol (wave 0) and deferred back-solve (wave 1).
//  - Unchanged from R2: async global_load_lds staging w/ counted vmcnt,
//    Y-form Riccati (V = Cxx + Fx^T W - Y^T Y), deferred back-solve.

constexpr int T_   = 64;
constexpr int B_   = 128;
constexpr int NS_  = 64;
constexpr int NC_  = 32;
constexpr int NSC_ = 96;

// ---- LDS layout (floats). Total 37160 floats = 148,640 B. ----
constexpr int OFF_VS   = 0;       // Vs [64][68]   (V, symmetric, stride 68)
constexpr int OFF_WS   = 4352;    // Ws [64][100]  (W = V F)  | fwd: Sfb[2][2304]
constexpr int OFF_QU   = 10752;   // Qu [32][100]  (Q rows 64..95 = [Qux|Quu])
constexpr int OFF_SS   = 13952;   // Ss [2][32][68] (Y buffers, double-buffered)
constexpr int OFF_LT   = 18304;   // LT [2][32][33] (chol factor^T, dbuf)
constexpr int OFF_INVD = 20416;   // invd[2][32]
constexpr int OFF_QV   = 20480;   // qv[96]+pad    | fwd: tau[96]
constexpr int OFF_HV   = 20580;   // hv[64]
constexpr int OFF_VV   = 20644;   // vv[64]+pad
constexpr int OFF_XNB  = 20712;   // xnb[64]
constexpr int OFF_FB   = 20776;   // Fbuf[2][6144] (F linear [64][96])
constexpr int OFF_CU   = 33064;   // Cu [3072]     (C rows 64..95, linear [32][96])
constexpr int OFF_CF   = 36136;   // cfb[2][512]   (c @ +0..95, f @ +256..319)
constexpr int SMEM_F   = 37160;

typedef __attribute__((address_space(3))) void*       lds_vp;
typedef const __attribute__((address_space(1))) void* gas_vp;

__device__ __forceinline__ void g2l16(const float* g, float* l) {
  __builtin_amdgcn_global_load_lds((gas_vp)g, (lds_vp)l, 16, 0, 0);
}

__device__ __forceinline__ float rdlane(float v, int l) {
  return __builtin_bit_cast(float, __builtin_amdgcn_readlane(__builtin_bit_cast(int, v), l));
}

#define ASM_WAIT(S) asm volatile("s_waitcnt " S ::: "memory")
#define BAR()       __builtin_amdgcn_s_barrier()

__global__ __launch_bounds__(512) void lqr_all(
    const float* __restrict__ Cg, const float* __restrict__ cvg,
    const float* __restrict__ Fg, const float* __restrict__ fvg,
    const float* __restrict__ x0g, float* __restrict__ outg,
    float* __restrict__ Sws)
{
  const int b    = blockIdx.x;
  const int tid  = threadIdx.x;
  const int wid  = tid >> 6;
  const int lane = tid & 63;

  __shared__ float smem[SMEM_F];
  float (*Vs)[68]  = (float(*)[68]) (smem + OFF_VS);
  float (*Ws)[100] = (float(*)[100])(smem + OFF_WS);
  float (*Qu)[100] = (float(*)[100])(smem + OFF_QU);
  float* qv = smem + OFF_QV;
  float* hv = smem + OFF_HV;
  float* vv = smem + OFF_VV;

  for (int e = tid; e < 4352; e += 512) smem[e] = 0.f;
  if (tid < 64) vv[tid] = 0.f;

  // deferred back-solve: S = L^{-T} Y from buffer pb, store to Sws for tbn
  auto backsolve = [&](int pb, size_t tbn, int col) {
    const float (*Sp)[68]  = (const float(*)[68])(smem + OFF_SS + pb * 2176);
    const float (*LTp)[33] = (const float(*)[33])(smem + OFF_LT + pb * 1056);
    const float* ivp = smem + OFF_INVD + pb * 32;
    float xr[32];
#pragma unroll
    for (int i = 0; i < 32; ++i) xr[i] = Sp[i][col];
#pragma unroll
    for (int i = 31; i >= 0; --i) {
      float v = xr[i];
#pragma unroll
      for (int k = i + 1; k < 32; ++k) v -= LTp[i][k] * xr[k];  // L^T
      xr[i] = v * ivp[i];
    }
    float* Sg = Sws + tbn * 2080;
#pragma unroll
    for (int i = 0; i < 32; ++i) Sg[i * 65 + col] = xr[i];
  };

  // ---- prologue staging: F_63, c_63, f_63 -> buffers[0] (5 instrs/wave)
  {
    const size_t tb0 = (size_t)(T_ - 1) * B_ + b;
    const float* Fbase = Fg + tb0 * (NS_ * NSC_);
#pragma unroll
    for (int r = 0; r < 3; ++r) {
      const int q = wid * 3 + r;
      g2l16(Fbase + q * 256 + lane * 4, smem + OFF_FB + q * 256);
    }
    const int o = lane * 4;
    g2l16(cvg + tb0 * 96 + (o < 96 ? o : 92), smem + OFF_CF);
    g2l16(fvg + tb0 * 64 + (o < 64 ? o : 60), smem + OFF_CF + 256);
  }

  int cur = 0;

  // VsD tile for waves 4-7 (2 rows x 8 cols): VsD = Cxx + Fx^T W
  const int tl   = (tid >= 256) ? (tid - 256) : 0;
  const int trow = (tl >> 3) * 2;
  const int tcol = (tl & 7) * 8;

  // ================= backward Riccati pass =================
  for (int t = T_ - 1; t >= 0; --t) {
    const size_t tb = (size_t)t * B_ + b;

    float4 cxa0, cxa1, cxb0, cxb1;               // Cxx regs (waves 4-7)

    // ---- TOP staging. waves 0-3: 7 async; waves 4-7: 6 async + 4 reg loads
    {
      const float* CuB = Cg + tb * 9216 + 64 * 96;
      if (wid < 4) {
        g2l16(CuB + (wid * 2)     * 256 + lane * 4, smem + OFF_CU + (wid * 2)     * 256);
        g2l16(CuB + (wid * 2 + 1) * 256 + lane * 4, smem + OFF_CU + (wid * 2 + 1) * 256);
      } else {
        g2l16(CuB + (4 + wid) * 256 + lane * 4, smem + OFF_CU + (4 + wid) * 256);
        const float* Cb = Cg + tb * 9216;
        cxa0 = *(const float4*)(Cb + trow * 96 + tcol);
        cxa1 = *(const float4*)(Cb + trow * 96 + tcol + 4);
        cxb0 = *(const float4*)(Cb + (trow + 1) * 96 + tcol);
        cxb1 = *(const float4*)(Cb + (trow + 1) * 96 + tcol + 4);
      }
      const int tp = (t > 0) ? (t - 1) : 0;
      const size_t tbp = (size_t)tp * B_ + b;
      const float* Fbase = Fg + tbp * (NS_ * NSC_);
      float* fdst = smem + OFF_FB + (cur ^ 1) * 6144;
#pragma unroll
      for (int r = 0; r < 3; ++r) {
        const int q = wid * 3 + r;
        g2l16(Fbase + q * 256 + lane * 4, fdst + q * 256);
      }
      float* cdst = smem + OFF_CF + (cur ^ 1) * 512;
      const int o = lane * 4;
      g2l16(cvg + tbp * 96 + (o < 96 ? o : 92), cdst);
      g2l16(fvg + tbp * 64 + (o < 64 ? o : 60), cdst + 256);
    }

    // W#1: drain prev-iter leftovers (F_t, cf_t); keep the new issues in flight
    if (wid < 4) { ASM_WAIT("vmcnt(7) lgkmcnt(0)"); } else { ASM_WAIT("vmcnt(10) lgkmcnt(0)"); }
    BAR();

    const float* Fb = smem + OFF_FB + cur * 6144;
    const float* cf = smem + OFF_CF + cur * 512;

    // ---- phase B: W = V F (all 512, 1x12 tiles); h = v + V f (tid<64 extra)
    {
      const int s  = tid >> 3;
      const int j0 = (tid & 7) * 12;
      float a[12];
#pragma unroll
      for (int j = 0; j < 12; ++j) a[j] = 0.f;
#pragma unroll 4
      for (int u = 0; u < 64; ++u) {
        const float vu = Vs[u][s];
        const float4 b0 = *(const float4*)(Fb + u * 96 + j0);
        const float4 b1 = *(const float4*)(Fb + u * 96 + j0 + 4);
        const float4 b2 = *(const float4*)(Fb + u * 96 + j0 + 8);
        a[0] += vu * b0.x; a[1] += vu * b0.y; a[2]  += vu * b0.z; a[3]  += vu * b0.w;
        a[4] += vu * b1.x; a[5] += vu * b1.y; a[6]  += vu * b1.z; a[7]  += vu * b1.w;
        a[8] += vu * b2.x; a[9] += vu * b2.y; a[10] += vu * b2.z; a[11] += vu * b2.w;
      }
      *(float4*)&Ws[s][j0]     = make_float4(a[0], a[1], a[2],  a[3]);
      *(float4*)&Ws[s][j0 + 4] = make_float4(a[4], a[5], a[6],  a[7]);
      *(float4*)&Ws[s][j0 + 8] = make_float4(a[8], a[9], a[10], a[11]);
    }
    if (tid < 64) {
      float acc = vv[tid];
#pragma unroll 8
      for (int u = 0; u < 64; ++u) acc += Vs[u][tid] * cf[256 + u];
      hv[tid] = acc;
    }

    // W#2: Cu staging + Cxx reg loads complete; keep F/cf_{t-1} (5) in flight
    ASM_WAIT("vmcnt(5) lgkmcnt(0)");
    BAR();

    // ---- phase Qu (waves 0-3): Qu = C[64:96,:] + Fu^T W
    //      || VsD (waves 4-7): Vs = Cxx + Fx^T W
    if (tid < 256) {
      const int i  = tid >> 3;
      const int j0 = (tid & 7) * 12;
      float a[12];
      {
        const float* cp = smem + OFF_CU + i * 96 + j0;
        const float4 c0 = *(const float4*)(cp);
        const float4 c1 = *(const float4*)(cp + 4);
        const float4 c2 = *(const float4*)(cp + 8);
        a[0] = c0.x; a[1] = c0.y; a[2]  = c0.z; a[3]  = c0.w;
        a[4] = c1.x; a[5] = c1.y; a[6]  = c1.z; a[7]  = c1.w;
        a[8] = c2.x; a[9] = c2.y; a[10] = c2.z; a[11] = c2.w;
      }
#pragma unroll 4
      for (int s2 = 0; s2 < 64; ++s2) {
        const float fu = Fb[s2 * 96 + 64 + i];
        const float4 w0 = *(const float4*)&Ws[s2][j0];
        const float4 w1 = *(const float4*)&Ws[s2][j0 + 4];
        const float4 w2 = *(const float4*)&Ws[s2][j0 + 8];
        a[0] += fu * w0.x; a[1] += fu * w0.y; a[2]  += fu * w0.z; a[3]  += fu * w0.w;
        a[4] += fu * w1.x; a[5] += fu * w1.y; a[6]  += fu * w1.z; a[7]  += fu * w1.w;
        a[8] += fu * w2.x; a[9] += fu * w2.y; a[10] += fu * w2.z; a[11] += fu * w2.w;
      }
      *(float4*)&Qu[i][j0]     = make_float4(a[0], a[1], a[2],  a[3]);
      *(float4*)&Qu[i][j0 + 4] = make_float4(a[4], a[5], a[6],  a[7]);
      *(float4*)&Qu[i][j0 + 8] = make_float4(a[8], a[9], a[10], a[11]);
    } else {
      float a0[8], a1[8];
      a0[0]=cxa0.x; a0[1]=cxa0.y; a0[2]=cxa0.z; a0[3]=cxa0.w;
      a0[4]=cxa1.x; a0[5]=cxa1.y; a0[6]=cxa1.z; a0[7]=cxa1.w;
      a1[0]=cxb0.x; a1[1]=cxb0.y; a1[2]=cxb0.z; a1[3]=cxb0.w;
      a1[4]=cxb1.x; a1[5]=cxb1.y; a1[6]=cxb1.z; a1[7]=cxb1.w;
#pragma unroll 4
      for (int u = 0; u < 64; ++u) {
        const float2 fx = *(const float2*)(Fb + u * 96 + trow);
        const float4 w0 = *(const float4*)&Ws[u][tcol];
        const float4 w1 = *(const float4*)&Ws[u][tcol + 4];
        a0[0] += fx.x * w0.x; a0[1] += fx.x * w0.y; a0[2] += fx.x * w0.z; a0[3] += fx.x * w0.w;
        a0[4] += fx.x * w1.x; a0[5] += fx.x * w1.y; a0[6] += fx.x * w1.z; a0[7] += fx.x * w1.w;
        a1[0] += fx.y * w0.x; a1[1] += fx.y * w0.y; a1[2] += fx.y * w0.z; a1[3] += fx.y * w0.w;
        a1[4] += fx.y * w1.x; a1[5] += fx.y * w1.y; a1[6] += fx.y * w1.z; a1[7] += fx.y * w1.w;
      }
      *(float4*)&Vs[trow][tcol]         = make_float4(a0[0], a0[1], a0[2], a0[3]);
      *(float4*)&Vs[trow][tcol + 4]     = make_float4(a0[4], a0[5], a0[6], a0[7]);
      *(float4*)&Vs[trow + 1][tcol]     = make_float4(a1[0], a1[1], a1[2], a1[3]);
      *(float4*)&Vs[trow + 1][tcol + 4] = make_float4(a1[4], a1[5], a1[6], a1[7]);
    }

    ASM_WAIT("lgkmcnt(0)");
    BAR();

    // ---- phase D (3-way concurrent):
    //   lanes 0-31 (wave 0): register Cholesky of Quu -> LT[cur], invd[cur]
    //   tid 64..128        : deferred back-solve of step t+1 -> Sws
    //   tid 129..224       : q = c + F^T h
    if (tid < 32) {
      const int i = tid;
      float a[32];
#pragma unroll
      for (int k = 0; k < 32; ++k) a[k] = Qu[i][64 + k];   // row i of Quu
      float (*LTc)[33] = (float(*)[33])(smem + OFF_LT + cur * 1056);
      float* ivc = smem + OFF_INVD + cur * 32;
#pragma unroll
      for (int j = 0; j < 32; ++j) {
        const float d   = rdlane(a[j], j);                 // updated diagonal
        const float rin = 1.0f / sqrtf(d);
        const float l   = a[j] * rin;                      // L[i][j] (valid i>=j)
        LTc[j][i] = l;                                     // lower-tri garbage never read
        if (i == 0) ivc[j] = rin;
#pragma unroll
        for (int k = j + 1; k < 32; ++k) {
          const float lkj = rdlane(l, k);                  // L[k][j] via SGPR bcast
          a[k] = fmaf(-l, lkj, a[k]);
        }
      }
    } else if (tid >= 64 && tid <= 128) {
      if (t != T_ - 1) backsolve(cur ^ 1, (size_t)(t + 1) * B_ + b, tid - 64);
    } else if (tid >= 129 && tid < 225) {
      const int j = tid - 129;                             // 0..95
      float acc = cf[j];
#pragma unroll 8
      for (int s2 = 0; s2 < 64; ++s2) acc += Fb[s2 * 96 + j] * hv[s2];
      qv[j] = acc;
    }

    ASM_WAIT("lgkmcnt(0)");
    BAR();

    // ---- phase E: forward solve Y = L^{-1}[Qux | qu] (tid<65) -> Ss[cur]
    if (tid < 65) {
      const float (*LTc)[33] = (const float(*)[33])(smem + OFF_LT + cur * 1056);
      const float* ivc = smem + OFF_INVD + cur * 32;
      float xr[32];
#pragma unroll
      for (int i = 0; i < 32; ++i) {
        float v = (tid < 64) ? Qu[i][tid] : qv[64 + i];
#pragma unroll
        for (int k = 0; k < i; ++k) v -= LTc[k][i] * xr[k];
        xr[i] = v * ivc[i];
      }
      float (*Sc)[68] = (float(*)[68])(smem + OFF_SS + cur * 2176);
#pragma unroll
      for (int i = 0; i < 32; ++i) Sc[i][tid] = xr[i];
    }

    ASM_WAIT("lgkmcnt(0)");
    BAR();

    // ---- phase F: V = VsD - Y^T Y (all 512, 2x4 tiles); vn = qx - Y^T y
    {
      const int vi0 = (tid >> 4) * 2, vj0 = (tid & 15) * 4;
      const float (*Sc)[68] = (const float(*)[68])(smem + OFF_SS + cur * 2176);
      float p0[4] = {0.f, 0.f, 0.f, 0.f}, p1[4] = {0.f, 0.f, 0.f, 0.f};
#pragma unroll 4
      for (int m = 0; m < 32; ++m) {
        const float2 ya = *(const float2*)&Sc[m][vi0];
        const float4 yb = *(const float4*)&Sc[m][vj0];
        p0[0] += ya.x * yb.x; p0[1] += ya.x * yb.y; p0[2] += ya.x * yb.z; p0[3] += ya.x * yb.w;
        p1[0] += ya.y * yb.x; p1[1] += ya.y * yb.y; p1[2] += ya.y * yb.z; p1[3] += ya.y * yb.w;
      }
      float4 v0 = *(const float4*)&Vs[vi0][vj0];
      float4 v1 = *(const float4*)&Vs[vi0 + 1][vj0];
      v0.x -= p0[0]; v0.y -= p0[1]; v0.z -= p0[2]; v0.w -= p0[3];
      v1.x -= p1[0]; v1.y -= p1[1]; v1.z -= p1[2]; v1.w -= p1[3];
      *(float4*)&Vs[vi0][vj0]     = v0;
      *(float4*)&Vs[vi0 + 1][vj0] = v1;
    }
    if (tid < 64) {
      const float (*Sc)[68] = (const float(*)[68])(smem + OFF_SS + cur * 2176);
      float acc = qv[tid];
#pragma unroll 4
      for (int m = 0; m < 32; ++m) acc -= Sc[m][tid] * Sc[m][64];
      vv[tid] = acc;
    }

    ASM_WAIT("lgkmcnt(0)");
    BAR();
    cur ^= 1;
  }

  // ---- epilogue: back-solve for t=0 (its Y/LT/invd live in buffer 1)
  ASM_WAIT("vmcnt(0) lgkmcnt(0)");
  BAR();
  if (tid < 65) backsolve(1, (size_t)b, tid);
  ASM_WAIT("vmcnt(0) lgkmcnt(0)");   // S stores must land before fwd re-reads
  BAR();

  // ================= forward rollout =================
  float* tf  = smem + OFF_QV;
  float* xnb = smem + OFF_XNB;
  if (tid < 64) tf[tid] = x0g[(size_t)b * 64 + tid];

  auto stage_fwd = [&](int ts, int nb) {
    const size_t tbs = (size_t)ts * B_ + b;
    const float* Sb = Sws + tbs * 2080;
    float* sdst = smem + OFF_WS + nb * 2304;
#pragma unroll
    for (int r = 0; r < 2; ++r) {
      int q = wid * 2 + r; if (q > 8) q = 8;
      const int off = q * 256 + lane * 4;
      g2l16(Sb + (off < 2080 ? off : 2076), sdst + q * 256);
    }
    const float* Fbase = Fg + tbs * (NS_ * NSC_);
    float* fdst = smem + OFF_FB + nb * 6144;
#pragma unroll
    for (int r = 0; r < 3; ++r) {
      const int q = wid * 3 + r;
      g2l16(Fbase + q * 256 + lane * 4, fdst + q * 256);
    }
    const int o = lane * 4;
    g2l16(fvg + tbs * 64 + (o < 64 ? o : 60), smem + OFF_CF + nb * 512);
  };

  stage_fwd(0, 0);
  cur = 0;
  for (int t = 0; t < T_; ++t) {
    const size_t tb = (size_t)t * B_ + b;
    stage_fwd((t < T_ - 1) ? t + 1 : T_ - 1, cur ^ 1);
    ASM_WAIT("vmcnt(6) lgkmcnt(0)");
    BAR();

    // u = -(S[:, :64] x + S[:, 64]) : 8 threads per control row
    if (tid < 256) {
      const int m = tid >> 3, l8 = tid & 7;
      const float* Sr = smem + OFF_WS + cur * 2304 + m * 65;
      float p = (l8 == 0) ? Sr[64] : 0.f;
      const int i0 = l8 * 8;
#pragma unroll
      for (int ii = 0; ii < 8; ++ii) p += Sr[i0 + ii] * tf[i0 + ii];
      p += __shfl_xor(p, 1); p += __shfl_xor(p, 2); p += __shfl_xor(p, 4);
      if (l8 == 0) tf[64 + m] = -p;
    }
    ASM_WAIT("lgkmcnt(0)");
    BAR();

    // emit tau; x_next = F tau + f : 8 threads per state row
    if (tid < 96) outg[tb * 96 + tid] = tf[tid];
    {
      const int s2 = tid >> 3, l8 = tid & 7;
      const float* Fr = smem + OFF_FB + cur * 6144 + s2 * 96 + l8 * 12;
      const float4 f0 = *(const float4*)(Fr);
      const float4 f1 = *(const float4*)(Fr + 4);
      const float4 f2 = *(const float4*)(Fr + 8);
      const int i0 = l8 * 12;
      float p = f0.x * tf[i0]     + f0.y * tf[i0 + 1] + f0.z * tf[i0 + 2]  + f0.w * tf[i0 + 3]
              + f1.x * tf[i0 + 4] + f1.y * tf[i0 + 5] + f1.z * tf[i0 + 6]  + f1.w * tf[i0 + 7]
              + f2.x * tf[i0 + 8] + f2.y * tf[i0 + 9] + f2.z * tf[i0 + 10] + f2.w * tf[i0 + 11];
      p += __shfl_xor(p, 1); p += __shfl_xor(p, 2); p += __shfl_xor(p, 4);
      if (l8 == 0) xnb[s2] = p + *(smem + OFF_CF + cur * 512 + s2);
    }
    ASM_WAIT("lgkmcnt(0)");
    BAR();
    if (tid < 64) tf[tid] = xnb[tid];
    cur ^= 1;
  }
}

extern "C" void kernel_launch(void* const* d_in, const int* in_sizes, int n_in,
                              void* d_out, int out_size, void* d_ws, size_t ws_size,
                              hipStream_t stream) {
  const float* C  = (const float*)d_in[0];
  const float* c  = (const float*)d_in[1];
  const float* F  = (const float*)d_in[2];
  const float* f  = (const float*)d_in[3];
  const float* x0 = (const float*)d_in[4];
  float* out = (float*)d_out;
  float* S   = (float*)d_ws;   // needs T*B*32*65*4 = 68.2 MB

  lqr_all<<<dim3(B_), dim3(512), 0, stream>>>(C, c, F, f, x0, out, S);
}